// Round 1
// baseline (400.925 us; speedup 1.0000x reference)
//
#include <hip/hip_runtime.h>
#include <hip/hip_bf16.h>

typedef float  f32x4  __attribute__((ext_vector_type(4)));
typedef __bf16 bf16x4 __attribute__((ext_vector_type(4)));
typedef __bf16 bf16x8 __attribute__((ext_vector_type(8)));

#define B_SZ  64
#define NTOK  341
#define NP    352          // padded tokens (mult of 16)
#define DM    768
#define NH    12
#define HD    64
#define MTOT  (B_SZ*NTOK)  // 21824
#define MP    21888        // 171*128 (padded rows)
#define EQKV  2304

__device__ __forceinline__ void gload_lds16(const __bf16* g, void* l) {
    __builtin_amdgcn_global_load_lds(
        (const __attribute__((address_space(1))) void*)g,
        (__attribute__((address_space(3))) void*)l, 16, 0, 0);
}

// ---------------- fp32 -> bf16 convert ----------------
__global__ void cvt_kernel(const float* __restrict__ in, __bf16* __restrict__ out, int n4) {
    int i = blockIdx.x * blockDim.x + threadIdx.x;
    const int stride = gridDim.x * blockDim.x;
    for (; i < n4; i += stride) {
        const float4 f = ((const float4*)in)[i];
        bf16x4 v;
        v[0] = (__bf16)f.x; v[1] = (__bf16)f.y; v[2] = (__bf16)f.z; v[3] = (__bf16)f.w;
        ((bf16x4*)out)[i] = v;
    }
}

// zero the padded K/V/Q rows (341..351) so masked/ignored lanes never see NaN
__global__ void zero_pads(__bf16* __restrict__ qb, __bf16* __restrict__ kb,
                          __bf16* __restrict__ vb) {
    const int i = blockIdx.x * 256 + threadIdx.x;   // < 64*12*11*64 = 540672
    const int bh  = i / 704;
    const int rem = i % 704;
    const int r = rem >> 6;
    const int d = rem & 63;
    const long off = ((long)bh * NP + (NTOK + r)) * (long)HD + d;
    const __bf16 z = (__bf16)0.f;
    qb[off] = z; kb[off] = z; vb[off] = z;
}

// ---------------- QKV GEMM: qkv[m,e] = sum_k x[m,k]*w[e,k] + b[e]; scatter to q/k/v ----------------
__global__ __launch_bounds__(256) void gemm_qkv(
    const __bf16* __restrict__ A, const __bf16* __restrict__ Bw,
    const float* __restrict__ bias,
    __bf16* __restrict__ qb, __bf16* __restrict__ kb2, __bf16* __restrict__ vb)
{
    __shared__ __bf16 As[128 * 32];
    __shared__ __bf16 Bs[128 * 32];
    const int tid = threadIdx.x;
    const int lane = tid & 63;
    const int w = tid >> 6;
    const int wm = w >> 1, wn = w & 1;
    const long a_row0 = (long)blockIdx.x * 128;
    const long b_row0 = (long)blockIdx.y * 128;

    const f32x4 fzero = {0.f, 0.f, 0.f, 0.f};
    f32x4 acc[4][4];
#pragma unroll
    for (int m = 0; m < 4; ++m)
#pragma unroll
        for (int n = 0; n < 4; ++n) acc[m][n] = fzero;

    for (int k0 = 0; k0 < DM; k0 += 32) {
#pragma unroll
        for (int i = 0; i < 2; ++i) {
            const int base = w * 2048 + i * 1024;       // wave-uniform LDS byte offset
            const int off  = base + lane * 16;          // this lane's target byte
            const int row  = off >> 6;
            const int kel  = k0 + ((off & 63) >> 1);
            gload_lds16(A  + (a_row0 + row) * DM + kel, (char*)As + base);
            gload_lds16(Bw + (b_row0 + row) * DM + kel, (char*)Bs + base);
        }
        __syncthreads();
        bf16x8 af[4], bfr[4];
#pragma unroll
        for (int m = 0; m < 4; ++m)
            af[m] = *(const bf16x8*)(As + (wm * 64 + m * 16 + (lane & 15)) * 32 + ((lane >> 4) * 8));
#pragma unroll
        for (int n = 0; n < 4; ++n)
            bfr[n] = *(const bf16x8*)(Bs + (wn * 64 + n * 16 + (lane & 15)) * 32 + ((lane >> 4) * 8));
#pragma unroll
        for (int m = 0; m < 4; ++m)
#pragma unroll
            for (int n = 0; n < 4; ++n)
                acc[m][n] = __builtin_amdgcn_mfma_f32_16x16x32_bf16(af[m], bfr[n], acc[m][n], 0, 0, 0);
        __syncthreads();
    }

    // epilogue: + bias, fold q-scale, scatter to [b,h,n,d] bf16 buffers
#pragma unroll
    for (int n = 0; n < 4; ++n) {
        const int col = wn * 64 + n * 16 + (lane & 15);
        const long ge = b_row0 + col;
        const int s   = (int)(ge / DM);
        const int rem = (int)(ge % DM);
        const int h = rem >> 6;
        const int d = rem & 63;
        const float bv = bias[ge];
#pragma unroll
        for (int m = 0; m < 4; ++m) {
            const long rbase = a_row0 + wm * 64 + m * 16 + ((lane >> 4) * 4);
#pragma unroll
            for (int r = 0; r < 4; ++r) {
                const long gm = rbase + r;
                if (gm < MTOT) {
                    const int bb = (int)(gm / NTOK);
                    const int nt = (int)(gm % NTOK);
                    const long off = (((long)bb * NH + h) * NP + nt) * (long)HD + d;
                    const float val = acc[m][n][r] + bv;
                    if (s == 0)      qb[off]  = (__bf16)(val * 0.125f);  // fold hd^-0.5
                    else if (s == 1) kb2[off] = (__bf16)val;
                    else             vb[off]  = (__bf16)val;
                }
            }
        }
    }
}

// ---------------- attention: per (b,h,qtile of 64 rows) ----------------
__global__ __launch_bounds__(256) void attn_kernel(
    const __bf16* __restrict__ qb, const __bf16* __restrict__ kb,
    const __bf16* __restrict__ vb, __bf16* __restrict__ ao)
{
    const int qt = blockIdx.x;   // 0..5
    const int h  = blockIdx.y;   // 0..11
    const int b  = blockIdx.z;   // 0..63
    const long bh = ((long)b * NH + h) * (long)NP * HD;

    __shared__ __bf16 vT[64][356];   // V^T, padded stride (712B: 8B-aligned, bank-spread)

    const int tid  = threadIdx.x;
    const int lane = tid & 63;
    const int w    = tid >> 6;

    // stage V^T (transpose during staging)
    for (int it = 0; it < 22; ++it) {
        const int c  = it * 256 + tid;        // < 5632
        const int n  = c >> 4;                // 0..351
        const int d4 = (c & 15) << 2;         // 0..60
        const bf16x4 e = *(const bf16x4*)(vb + bh + (long)n * HD + d4);
        vT[d4 + 0][n] = e[0];
        vT[d4 + 1][n] = e[1];
        vT[d4 + 2][n] = e[2];
        vT[d4 + 3][n] = e[3];
    }
    __syncthreads();

    const int q0 = qt * 64 + w * 16;
    if (q0 >= NTOK) return;   // whole wave is padding

    const int g  = lane >> 4;    // k-group 0..3
    const int qi = lane & 15;
    int qrow = q0 + qi; if (qrow > NP - 1) qrow = NP - 1;

    const __bf16* qsrc = qb + bh + (long)qrow * HD + g * 8;
    const bf16x8 qf0 = *(const bf16x8*)(qsrc);
    const bf16x8 qf1 = *(const bf16x8*)(qsrc + 32);

    // S^T = K * Q^T : lane holds q = lane&15, k = kf*16 + g*4 + reg
    f32x4 st[22];
    const f32x4 fzero = {0.f, 0.f, 0.f, 0.f};
#pragma unroll
    for (int kf = 0; kf < 22; ++kf) {
        const __bf16* ksrc = kb + bh + (long)(kf * 16 + qi) * HD + g * 8;
        const bf16x8 k0v = *(const bf16x8*)(ksrc);
        const bf16x8 k1v = *(const bf16x8*)(ksrc + 32);
        f32x4 a = fzero;
        a = __builtin_amdgcn_mfma_f32_16x16x32_bf16(k0v, qf0, a, 0, 0, 0);
        a = __builtin_amdgcn_mfma_f32_16x16x32_bf16(k1v, qf1, a, 0, 0, 0);
        st[kf] = a;
    }

    // prefix-mask limit per q row
    const int qg = q0 + qi;
    int limit;
    if (qg == 0)       limit = NTOK;
    else if (qg < 5)   limit = 5;
    else if (qg < 21)  limit = 21;
    else if (qg < 85)  limit = 85;
    else               limit = NTOK;   // includes pad rows (unwritten)

    float mx = -1e30f;
#pragma unroll
    for (int kf = 0; kf < 22; ++kf)
#pragma unroll
        for (int r = 0; r < 4; ++r) {
            const int k = kf * 16 + g * 4 + r;
            if (k < limit) mx = fmaxf(mx, st[kf][r]);
        }
    mx = fmaxf(mx, __shfl_xor(mx, 16));
    mx = fmaxf(mx, __shfl_xor(mx, 32));

    float sum = 0.f;
#pragma unroll
    for (int kf = 0; kf < 22; ++kf)
#pragma unroll
        for (int r = 0; r < 4; ++r) {
            const int k = kf * 16 + g * 4 + r;
            const float p = (k < limit) ? __expf(st[kf][r] - mx) : 0.f;
            st[kf][r] = p;
            sum += p;
        }
    sum += __shfl_xor(sum, 16);
    sum += __shfl_xor(sum, 32);
    const float rinv = 1.f / sum;

    // O^T = V^T * P^T  (k-permutation psi(g,i) = g*4 + i%4 + 16*(i/4) on BOTH operands)
    f32x4 oacc[4];
#pragma unroll
    for (int db = 0; db < 4; ++db) oacc[db] = fzero;

#pragma unroll
    for (int j = 0; j < 11; ++j) {
        bf16x8 pf;
#pragma unroll
        for (int r = 0; r < 4; ++r) {
            pf[r]     = (__bf16)st[2 * j][r];
            pf[4 + r] = (__bf16)st[2 * j + 1][r];
        }
#pragma unroll
        for (int db = 0; db < 4; ++db) {
            const int d = db * 16 + qi;
            const bf16x4 lo = *(const bf16x4*)&vT[d][j * 32 + g * 4];
            const bf16x4 hi = *(const bf16x4*)&vT[d][j * 32 + 16 + g * 4];
            bf16x8 vf;
#pragma unroll
            for (int r = 0; r < 4; ++r) { vf[r] = lo[r]; vf[4 + r] = hi[r]; }
            oacc[db] = __builtin_amdgcn_mfma_f32_16x16x32_bf16(vf, pf, oacc[db], 0, 0, 0);
        }
    }

    if (qg < NTOK) {
        const long orow = ((long)b * NTOK + qg) * DM + h * HD;
#pragma unroll
        for (int db = 0; db < 4; ++db) {
            const int d = db * 16 + g * 4;
#pragma unroll
            for (int r = 0; r < 4; ++r)
                ao[orow + d + r] = (__bf16)(oacc[db][r] * rinv);
        }
    }
}

// ---------------- proj GEMM: out[m,e] = sum_d ao[m,d]*wp[e,d] + b[e] (fp32 out) ----------------
__global__ __launch_bounds__(256) void gemm_proj(
    const __bf16* __restrict__ A, const __bf16* __restrict__ Bw,
    const float* __restrict__ bias, float* __restrict__ out)
{
    __shared__ __bf16 As[128 * 32];
    __shared__ __bf16 Bs[128 * 32];
    const int tid = threadIdx.x;
    const int lane = tid & 63;
    const int w = tid >> 6;
    const int wm = w >> 1, wn = w & 1;
    const long a_row0 = (long)blockIdx.x * 128;
    const long b_row0 = (long)blockIdx.y * 128;

    const f32x4 fzero = {0.f, 0.f, 0.f, 0.f};
    f32x4 acc[4][4];
#pragma unroll
    for (int m = 0; m < 4; ++m)
#pragma unroll
        for (int n = 0; n < 4; ++n) acc[m][n] = fzero;

    for (int k0 = 0; k0 < DM; k0 += 32) {
#pragma unroll
        for (int i = 0; i < 2; ++i) {
            const int base = w * 2048 + i * 1024;
            const int off  = base + lane * 16;
            const int row  = off >> 6;
            const int kel  = k0 + ((off & 63) >> 1);
            gload_lds16(A  + (a_row0 + row) * DM + kel, (char*)As + base);
            gload_lds16(Bw + (b_row0 + row) * DM + kel, (char*)Bs + base);
        }
        __syncthreads();
        bf16x8 af[4], bfr[4];
#pragma unroll
        for (int m = 0; m < 4; ++m)
            af[m] = *(const bf16x8*)(As + (wm * 64 + m * 16 + (lane & 15)) * 32 + ((lane >> 4) * 8));
#pragma unroll
        for (int n = 0; n < 4; ++n)
            bfr[n] = *(const bf16x8*)(Bs + (wn * 64 + n * 16 + (lane & 15)) * 32 + ((lane >> 4) * 8));
#pragma unroll
        for (int m = 0; m < 4; ++m)
#pragma unroll
            for (int n = 0; n < 4; ++n)
                acc[m][n] = __builtin_amdgcn_mfma_f32_16x16x32_bf16(af[m], bfr[n], acc[m][n], 0, 0, 0);
        __syncthreads();
    }

#pragma unroll
    for (int n = 0; n < 4; ++n) {
        const int col = wn * 64 + n * 16 + (lane & 15);
        const long ge = b_row0 + col;
        const float bv = bias[ge];
#pragma unroll
        for (int m = 0; m < 4; ++m) {
            const long rbase = a_row0 + wm * 64 + m * 16 + ((lane >> 4) * 4);
#pragma unroll
            for (int r = 0; r < 4; ++r) {
                const long gm = rbase + r;
                if (gm < MTOT) out[gm * DM + ge] = acc[m][n][r] + bv;
            }
        }
    }
}

extern "C" void kernel_launch(void* const* d_in, const int* in_sizes, int n_in,
                              void* d_out, int out_size, void* d_ws, size_t ws_size,
                              hipStream_t stream) {
    const float* x      = (const float*)d_in[0];
    const float* qkv_w  = (const float*)d_in[1];
    const float* qkv_b  = (const float*)d_in[2];
    const float* proj_w = (const float*)d_in[3];
    const float* proj_b = (const float*)d_in[4];
    float* out = (float*)d_out;

    char* ws = (char*)d_ws;
    constexpr size_t XB_BYTES = (size_t)MP * DM * 2;          // 33,619,968 (also reused as attn-out)
    constexpr size_t WQ_OFF   = XB_BYTES;
    constexpr size_t WP_OFF   = WQ_OFF + (size_t)EQKV * DM * 2;
    constexpr size_t QB_OFF   = WP_OFF + (size_t)DM * DM * 2;
    constexpr size_t QKV_BYTES = (size_t)B_SZ * NH * NP * HD * 2;  // 34,603,008 each
    constexpr size_t KB_OFF   = QB_OFF + QKV_BYTES;
    constexpr size_t VB_OFF   = KB_OFF + QKV_BYTES;

    __bf16* xb = (__bf16*)(ws);            // x in bf16; later aliased as attention output
    __bf16* wq = (__bf16*)(ws + WQ_OFF);
    __bf16* wp = (__bf16*)(ws + WP_OFF);
    __bf16* qb = (__bf16*)(ws + QB_OFF);
    __bf16* kb = (__bf16*)(ws + KB_OFF);
    __bf16* vb = (__bf16*)(ws + VB_OFF);

    cvt_kernel<<<2048, 256, 0, stream>>>(x,      xb, MTOT * DM / 4);
    cvt_kernel<<<1728, 256, 0, stream>>>(qkv_w,  wq, EQKV * DM / 4);
    cvt_kernel<<<576,  256, 0, stream>>>(proj_w, wp, DM * DM / 4);
    zero_pads<<<2112, 256, 0, stream>>>(qb, kb, vb);

    gemm_qkv<<<dim3(171, 18), 256, 0, stream>>>(xb, wq, qkv_b, qb, kb, vb);
    attn_kernel<<<dim3(6, NH, B_SZ), 256, 0, stream>>>(qb, kb, vb, xb /* attn out aliases xb */);
    gemm_proj<<<dim3(171, 6), 256, 0, stream>>>(xb, wp, proj_b, out);
}